// Round 5
// baseline (186.368 us; speedup 1.0000x reference)
//
#include <hip/hip_runtime.h>
#include <hip/hip_bf16.h>

typedef float v4f __attribute__((ext_vector_type(4)));
typedef float f32x4 __attribute__((ext_vector_type(4)));
typedef unsigned short u16;
typedef unsigned short us4 __attribute__((ext_vector_type(4)));
typedef unsigned short us8 __attribute__((ext_vector_type(8)));
typedef short s16x8 __attribute__((ext_vector_type(8)));

#define N_NODES 10000
#define N_EDGES 160000

// XOR-swizzle on ushort index: spreads stride-128B rows across bank quads.
#define SWZ(idx, row) ((idx) ^ (((row) & 7) << 3))

__device__ __forceinline__ u16 f2b(float x) {
  union { float f; unsigned u; } v; v.f = x;
  unsigned r = v.u + 0x7fffu + ((v.u >> 16) & 1u);
  return (u16)(r >> 16);
}
__device__ __forceinline__ float b2f(u16 u) {
  union { unsigned u; float f; } v; v.u = ((unsigned)u) << 16; return v.f;
}
__device__ __forceinline__ float silu_f(float x) { return x / (1.0f + __expf(-x)); }

// lgkm-only barrier: keeps global (vmcnt) loads in flight across it.
__device__ __forceinline__ void bar_lgkm() {
  asm volatile("s_waitcnt lgkmcnt(0)" ::: "memory");
  __builtin_amdgcn_s_barrier();
}

// ---------------- prep: pack weight A-fragments (lane-major, bf16) ----------
// frag f: lane holds A[ut*16 + (lane&15)][kw*32 + (lane>>4)*8 + j], j=0..7.
// Sections (8-ushort frags): L2 @0 (512), L3 @512, L4 @1024 (1024),
// NS @2048 (1024), NV @3072 (1024).
__global__ __launch_bounds__(256) void prep_kernel(
    const float* __restrict__ fcw1, const float* __restrict__ fcw2,
    const float* __restrict__ fcw3,
    const float* __restrict__ W10, const float* __restrict__ W20,
    const float* __restrict__ W11, const float* __restrict__ W21,
    u16* __restrict__ prep)
{
  const int fid = blockIdx.x * 256 + threadIdx.x;   // 0..4095
  int f, sec;
  if (fid < 512)       { sec = 0; f = fid; }
  else if (fid < 1024) { sec = 1; f = fid - 512; }
  else if (fid < 2048) { sec = 2; f = fid - 1024; }
  else if (fid < 3072) { sec = 3; f = fid - 2048; }
  else                 { sec = 4; f = fid - 3072; }
  const int lane = f & 63, kw = (f >> 6) & 1, ut = f >> 7;
  us8 vals;
  #pragma unroll
  for (int j = 0; j < 8; ++j) {
    const int k = kw * 32 + (lane >> 4) * 8 + j;
    float v;
    if (sec == 0) v = fcw1[k * 64 + ut * 16 + (lane & 15)];
    else if (sec == 1) v = fcw2[k * 64 + ut * 16 + (lane & 15)];
    else if (sec == 2) {
      const int col = (ut < 4) ? (ut * 16 + (lane & 15)) : (192 + (ut - 4) * 16 + (lane & 15));
      v = fcw3[k * 256 + col];
    } else if (sec == 3) {
      const int u = ut * 16 + (lane & 15);
      v = (u < 64) ? W10[k * 64 + u] : W20[k * 64 + (u - 64)];
    } else {
      const int u = ut * 16 + (lane & 15);
      v = (u < 64) ? W11[k * 64 + u] : W21[k * 64 + (u - 64)];
    }
    vals[j] = f2b(v);
  }
  *(us8*)&prep[(size_t)fid * 8] = vals;
}

// ---------------- node kernel: 16 nodes/block, 625 blocks -------------------
// Atab[n][256] = [s1 | v1x | v1y | v1z] bf16 (x0.125 folded); Btab: s2,v2.
__global__ __launch_bounds__(256) void node_kernel(
    const float* __restrict__ nf,
    const u16* __restrict__ prepNS, const u16* __restrict__ prepNV,
    const float* __restrict__ Wm1,
    u16* __restrict__ Atab, u16* __restrict__ Btab, float* __restrict__ out)
{
  __shared__ u16 Ss[1024];
  __shared__ u16 Vs[3][1024];
  const int tid = threadIdx.x, w = tid >> 6, lane = tid & 63;
  const int nb = blockIdx.x;

  // stage + f32->bf16 + de-interleave v (col constant per thread across iters)
  #pragma unroll
  for (int it = 0; it < 4; ++it) {
    const int flat = it * 1024 + tid * 4;
    const int nl = flat >> 8;            // 0..15
    const int col = flat & 255;
    const v4f x = *(const v4f*)&nf[((size_t)(nb * 16 + nl)) * 256 + col];
    #pragma unroll
    for (int i = 0; i < 4; ++i) {
      const int c2 = col + i;
      const u16 b = f2b(x[i]);
      if (c2 < 64) Ss[SWZ(nl * 64 + c2, nl)] = b;
      else {
        const int cc = c2 - 64, c = cc / 3, m = cc - c * 3;
        Vs[m][SWZ(nl * 64 + c, nl)] = b;
      }
    }
  }
  __syncthreads();

  const int nr = lane & 15, kg = (lane >> 4) * 8;
  const u16* plane = (w == 0) ? Ss : Vs[w - 1];   // wave = pass (s,x,y,z)
  const u16* pw = (w == 0) ? prepNS : prepNV;
  const s16x8 b0 = *(const s16x8*)&plane[SWZ(nr * 64 + kg, nr)];
  const s16x8 b1 = *(const s16x8*)&plane[SWZ(nr * 64 + 32 + kg, nr)];
  const int node = nb * 16 + nr;
  #pragma unroll
  for (int utg = 0; utg < 8; ++utg) {
    const s16x8 a0 = *(const s16x8*)&pw[((utg * 2 + 0) * 64 + lane) * 8];
    const s16x8 a1 = *(const s16x8*)&pw[((utg * 2 + 1) * 64 + lane) * 8];
    f32x4 acc = {0.f, 0.f, 0.f, 0.f};
    acc = __builtin_amdgcn_mfma_f32_16x16x32_bf16(a0, b0, acc, 0, 0, 0);
    acc = __builtin_amdgcn_mfma_f32_16x16x32_bf16(a1, b1, acc, 0, 0, 0);
    us4 st;
    #pragma unroll
    for (int j = 0; j < 4; ++j) st[j] = f2b(acc[j] * 0.125f);
    u16* tab = (utg < 4) ? Atab : Btab;
    const int ch = w * 64 + (utg & 3) * 16 + (lane >> 4) * 4;
    *(us4*)&tab[(size_t)node * 256 + ch] = st;
  }

  // mvec (Vs untouched since staging barrier)
  if (tid < 48) {
    const int nl3 = tid / 3, m = tid - nl3 * 3;
    float acc = 0.f;
    #pragma unroll 8
    for (int c = 0; c < 64; ++c)
      acc += b2f(Vs[m][SWZ(nl3 * 64 + c, nl3)]) * Wm1[c];
    out[(nb * 16 + nl3) * 4 + 1 + m] = acc * 0.125f;
  }
}

// layer: Hin -> Hout (swizzled [edge][k] bf16), A-frags in VGPRs
__device__ __forceinline__ void mfma_layer(const u16* Hin, u16* Hout,
                                           s16x8 a0, s16x8 a1, int w, int lane) {
  const int er = lane & 15, kg = (lane >> 4) * 8;
  #pragma unroll
  for (int et = 0; et < 4; ++et) {
    const int e = et * 16 + er;
    const s16x8 b0 = *(const s16x8*)&Hin[SWZ(e * 64 + kg, e)];
    const s16x8 b1 = *(const s16x8*)&Hin[SWZ(e * 64 + 32 + kg, e)];
    f32x4 acc = {0.f, 0.f, 0.f, 0.f};
    acc = __builtin_amdgcn_mfma_f32_16x16x32_bf16(a0, b0, acc, 0, 0, 0);
    acc = __builtin_amdgcn_mfma_f32_16x16x32_bf16(a1, b1, acc, 0, 0, 0);
    us4 st;
    #pragma unroll
    for (int j = 0; j < 4; ++j) st[j] = f2b(silu_f(acc[j] * 0.125f));
    *(us4*)&Hout[SWZ(e * 64 + w * 16 + (lane >> 4) * 4, e)] = st;
  }
}

// ---------------- edge kernel: prefetched gather + MFMA MLP -----------------
__global__ __launch_bounds__(256, 3) void edge_kernel(
    const float* __restrict__ edge_attrs,
    const float* __restrict__ edge_feats,
    const int*   __restrict__ edge_index,
    const float* __restrict__ fcw0,
    const u16*   __restrict__ prep,     // L2 @0, L3 @512*8, L4 @1024*8
    const float* __restrict__ Wf,
    const u16*   __restrict__ Atab, const u16* __restrict__ Btab,
    float* __restrict__ charges, float* __restrict__ p_out)
{
  __shared__ float F[512];
  __shared__ float W0L[512];
  __shared__ u16 HA[4096], HB[4096];
  __shared__ int sndL[64], rcvL[64];
  __shared__ float y0L[64], yxL[64], yyL[64], yzL[64];
  __shared__ float Psum[256];          // [wave][edge] partials

  const int tid = threadIdx.x, w = tid >> 6, lane = tid & 63;
  const int ebase = blockIdx.x * 64;
  const int er = lane & 15, kg = (lane >> 4) * 8;
  const int cb = w * 16 + (lane >> 4) * 4;

  // (1) index loads (oldest in vmcnt queue)
  int snd[4], rcv[4];
  #pragma unroll
  for (int et = 0; et < 4; ++et) {
    snd[et] = edge_index[ebase + et * 16 + er];
    rcv[et] = edge_index[N_EDGES + ebase + et * 16 + er];
  }
  // (2) staging + fragment loads (before gathers so later waits don't drain them)
  v4f eaV = {0.f,0.f,0.f,0.f}, f0V = {0.f,0.f,0.f,0.f}, f1V = {0.f,0.f,0.f,0.f};
  if (tid < 64) {
    eaV = *(const v4f*)&edge_attrs[(size_t)(ebase + tid) * 4];
    f0V = *(const v4f*)&edge_feats[(size_t)(ebase + tid) * 8];
    f1V = *(const v4f*)&edge_feats[(size_t)(ebase + tid) * 8 + 4];
  }
  const float w0a = fcw0[tid], w0b = fcw0[256 + tid];
  const u16* pL2 = prep;
  const u16* pL3 = prep + 512 * 8;
  const u16* pL4 = prep + 1024 * 8;
  const s16x8 a2_0 = *(const s16x8*)&pL2[((w * 2 + 0) * 64 + lane) * 8];
  const s16x8 a2_1 = *(const s16x8*)&pL2[((w * 2 + 1) * 64 + lane) * 8];
  const s16x8 a3_0 = *(const s16x8*)&pL3[((w * 2 + 0) * 64 + lane) * 8];
  const s16x8 a3_1 = *(const s16x8*)&pL3[((w * 2 + 1) * 64 + lane) * 8];
  const s16x8 as0 = *(const s16x8*)&pL4[((w * 2 + 0) * 64 + lane) * 8];
  const s16x8 as1 = *(const s16x8*)&pL4[((w * 2 + 1) * 64 + lane) * 8];
  const s16x8 av0 = *(const s16x8*)&pL4[(((4 + w) * 2 + 0) * 64 + lane) * 8];
  const s16x8 av1 = *(const s16x8*)&pL4[(((4 + w) * 2 + 1) * 64 + lane) * 8];
  const v4f wfA = *(const v4f*)&Wf[cb];
  const v4f wfBr = *(const v4f*)&Wf[64 + cb];

  // (3) gathers (newest; consumed after L4 -> hidden under whole MLP)
  us4 gAs[4], gAx[4], gAy[4], gAz[4], gBs[4], gBx[4], gBy[4], gBz[4];
  #pragma unroll
  for (int et = 0; et < 4; ++et) {
    const u16* ra = Atab + (size_t)snd[et] * 256;
    const u16* rb = Btab + (size_t)rcv[et] * 256;
    gAs[et] = *(const us4*)&ra[cb];       gAx[et] = *(const us4*)&ra[64 + cb];
    gAy[et] = *(const us4*)&ra[128 + cb]; gAz[et] = *(const us4*)&ra[192 + cb];
    gBs[et] = *(const us4*)&rb[cb];       gBx[et] = *(const us4*)&rb[64 + cb];
    gBy[et] = *(const us4*)&rb[128 + cb]; gBz[et] = *(const us4*)&rb[192 + cb];
  }
  __builtin_amdgcn_sched_barrier(0);     // pin gather issue point

  // (4) LDS staging writes
  if (tid < 64) {
    y0L[tid] = eaV[0]; yxL[tid] = eaV[1]; yyL[tid] = eaV[2]; yzL[tid] = eaV[3];
    #pragma unroll
    for (int k = 0; k < 4; ++k) { F[k * 64 + tid] = f0V[k]; F[(k + 4) * 64 + tid] = f1V[k]; }
    #pragma unroll
    for (int et = 0; et < 4; ++et) {
      sndL[et * 16 + (tid & 15)] = snd[et];
      rcvL[et * 16 + (tid & 15)] = rcv[et];
    }
  }
  W0L[tid] = w0a; W0L[256 + tid] = w0b;
  bar_lgkm();

  // ---- layer 1 (VALU, K=8): wave w -> units w*16..w*16+15 for all 64 edges
  {
    const int e = lane;
    float acc[16];
    #pragma unroll
    for (int j = 0; j < 16; ++j) acc[j] = 0.f;
    #pragma unroll
    for (int k = 0; k < 8; ++k) {
      const float fv = F[k * 64 + e];
      #pragma unroll
      for (int q = 0; q < 4; ++q) {
        const v4f wr = *(const v4f*)&W0L[k * 64 + w * 16 + q * 4];
        #pragma unroll
        for (int j = 0; j < 4; ++j) acc[q * 4 + j] += fv * wr[j];
      }
    }
    us8 o0, o1;
    #pragma unroll
    for (int j = 0; j < 8; ++j) {
      o0[j] = f2b(silu_f(acc[j] * 0.35355339059327373f));
      o1[j] = f2b(silu_f(acc[8 + j] * 0.35355339059327373f));
    }
    *(us8*)&HA[SWZ(e * 64 + w * 16, e)] = o0;
    *(us8*)&HA[SWZ(e * 64 + w * 16 + 8, e)] = o1;
  }
  bar_lgkm();
  mfma_layer(HA, HB, a2_0, a2_1, w, lane);   // layer 2
  bar_lgkm();
  mfma_layer(HB, HA, a3_0, a3_1, w, lane);   // layer 3
  bar_lgkm();

  // ---- layer 4 (MFMA) + contraction with prefetched gathers
  v4f wfB = wfBr;
  #pragma unroll
  for (int j = 0; j < 4; ++j) wfB[j] *= 0.5773502691896258f;

  #pragma unroll
  for (int et = 0; et < 4; ++et) {
    const int e = et * 16 + er;
    const s16x8 b0 = *(const s16x8*)&HA[SWZ(e * 64 + kg, e)];
    const s16x8 b1 = *(const s16x8*)&HA[SWZ(e * 64 + 32 + kg, e)];
    f32x4 accS = {0.f, 0.f, 0.f, 0.f}, accV = {0.f, 0.f, 0.f, 0.f};
    accS = __builtin_amdgcn_mfma_f32_16x16x32_bf16(as0, b0, accS, 0, 0, 0);
    accS = __builtin_amdgcn_mfma_f32_16x16x32_bf16(as1, b1, accS, 0, 0, 0);
    accV = __builtin_amdgcn_mfma_f32_16x16x32_bf16(av0, b0, accV, 0, 0, 0);
    accV = __builtin_amdgcn_mfma_f32_16x16x32_bf16(av1, b1, accV, 0, 0, 0);

    const float y0 = y0L[e], yx = yxL[e], yy = yyL[e], yz = yzL[e];
    float part = 0.f;
    #pragma unroll
    for (int j = 0; j < 4; ++j) {
      const float bs = b2f(gAs[et][j]) + b2f(gBs[et][j]);
      const float bv = (b2f(gAx[et][j]) + b2f(gBx[et][j])) * yx +
                       (b2f(gAy[et][j]) + b2f(gBy[et][j])) * yy +
                       (b2f(gAz[et][j]) + b2f(gBz[et][j])) * yz;
      part += accS[j] * bs * y0 * wfA[j] + accV[j] * bv * wfB[j];
    }
    part += __shfl_xor(part, 16);
    part += __shfl_xor(part, 32);
    if (lane < 16) Psum[w * 64 + et * 16 + lane] = part;
  }
  bar_lgkm();
  if (tid < 64) {
    // fold: 0.125 (layer-4 1/sqrt(64)) / sqrt(128) / 40
    const float p = (Psum[tid] + Psum[64 + tid] + Psum[128 + tid] + Psum[192 + tid])
                    * 2.7621358640766505e-4f;
    p_out[ebase + tid] = p;
    atomicAdd(&charges[rcvL[tid]], p);
    atomicAdd(&charges[sndL[tid]], -p);
  }
}

// ---------------- finalize ----------------
__global__ void finalize_kernel(const float* __restrict__ charges, float* __restrict__ out) {
  const int n = blockIdx.x * 256 + threadIdx.x;
  if (n < N_NODES) out[n * 4] = charges[n];
}

extern "C" void kernel_launch(void* const* d_in, const int* in_sizes, int n_in,
                              void* d_out, int out_size, void* d_ws, size_t ws_size,
                              hipStream_t stream) {
  const float* node_feats = (const float*)d_in[1];
  const float* edge_attrs = (const float*)d_in[2];
  const float* edge_feats = (const float*)d_in[3];
  const int*   edge_index = (const int*)d_in[4];
  const float* W10  = (const float*)d_in[8];
  const float* W11  = (const float*)d_in[9];
  const float* W20  = (const float*)d_in[10];
  const float* W21  = (const float*)d_in[11];
  const float* fcw0 = (const float*)d_in[12];
  const float* fcw1 = (const float*)d_in[13];
  const float* fcw2 = (const float*)d_in[14];
  const float* fcw3 = (const float*)d_in[15];
  const float* Wf   = (const float*)d_in[16];
  const float* Wm1  = (const float*)d_in[17];
  float* out = (float*)d_out;

  char* ws = (char*)d_ws;
  u16*   Atab    = (u16*)ws;                              // 10000*256 u16
  u16*   Btab    = (u16*)(ws + 5120000);
  float* charges = (float*)(ws + 10240000);
  u16*   prep    = (u16*)(ws + 10280000);                 // 4096 frags * 16B

  prep_kernel<<<16, 256, 0, stream>>>(fcw1, fcw2, fcw3, W10, W20, W11, W21, prep);
  hipMemsetAsync(charges, 0, N_NODES * sizeof(float), stream);
  node_kernel<<<625, 256, 0, stream>>>(node_feats, prep + 2048 * 8, prep + 3072 * 8,
                                       Wm1, Atab, Btab, out);
  edge_kernel<<<2500, 256, 0, stream>>>(edge_attrs, edge_feats, edge_index,
                                        fcw0, prep, Wf, Atab, Btab,
                                        charges, out + 40000);
  finalize_kernel<<<40, 256, 0, stream>>>(charges, out);
}